// Round 4
// baseline (46.457 us; speedup 1.0000x reference)
//
#include <hip/hip_runtime.h>

constexpr int N = 8192;
// MIN_DIST = RADIUS*2*scale = 1.0f
// TRI = N(N+1)/2, exact in f32
constexpr float TRI = 33558528.0f;

__device__ __forceinline__ float fsqrt(float v) { return __builtin_amdgcn_sqrtf(v); }

// Fused kernel.
//  blocks [0,512):    pair tiles — 16 rows each: {8b..8b+7} (top) + {N-8b-8..N-8b-1}
//                     (bot), upper-triangle scan j >= i. Per-row outputs:
//                       row_sd[i] = sum_{j>=i} d(i,j)
//                       row_sm[i] = sum_{j>=i} min(d,1)
//  blocks [512,768):  masked-prefix-run correction, 8 rows per wave:
//                       row_corr[i] = sum over run [i,k) of (1-d), k = first d>1.
__global__ __launch_bounds__(256, 4)
void main_kernel(const float* __restrict__ x, const float* __restrict__ y,
                 const float* __restrict__ z,
                 float* __restrict__ row_sd, float* __restrict__ row_sm,
                 float* __restrict__ row_corr) {
    const int tid  = threadIdx.x;
    const int lane = tid & 63;
    const int wave = tid >> 6;

    if (blockIdx.x < 512) {
        const int b       = blockIdx.x;
        const int topBase = 8 * b;            // 0..4088
        const int botBase = N - 8 * (b + 1);  // 8184..4096

        // Row coordinates: block-uniform reads -> scalar regs.
        float xr[16], yr[16], zr[16];
#pragma unroll
        for (int r = 0; r < 8; ++r) {
            xr[r]     = x[topBase + r]; yr[r]     = y[topBase + r]; zr[r]     = z[topBase + r];
            xr[8 + r] = x[botBase + r]; yr[8 + r] = y[botBase + r]; zr[8 + r] = z[botBase + r];
        }
        float sd[16], sm[16];
#pragma unroll
        for (int r = 0; r < 16; ++r) { sd[r] = 0.f; sm[r] = 0.f; }

#pragma unroll
        for (int g = 0; g < 2; ++g) {
            const int base = g ? botBase : topBase;
            const int ro   = g * 8;

            // head chunk [base, base+512): predicated vs diagonal and N
            {
                const int   j1 = base + tid;
                const int   j2 = base + 256 + tid;
                const int   c1 = j1 < N ? j1 : N - 1;
                const int   c2 = j2 < N ? j2 : N - 1;
                const float ax = x[c1], ay = y[c1], az = z[c1];
                const float bx = x[c2], by = y[c2], bz = z[c2];
#pragma unroll
                for (int r = 0; r < 8; ++r) {
                    {
                        const float dx = ax - xr[ro + r], dy = ay - yr[ro + r], dz = az - zr[ro + r];
                        const float d  = fsqrt(dx * dx + dy * dy + dz * dz);
                        if (tid >= r && j1 < N) { sd[ro + r] += d; sm[ro + r] += fminf(d, 1.f); }
                    }
                    {
                        const float dx = bx - xr[ro + r], dy = by - yr[ro + r], dz = bz - zr[ro + r];
                        const float d  = fsqrt(dx * dx + dy * dy + dz * dz);
                        if (j2 < N) { sd[ro + r] += d; sm[ro + r] += fminf(d, 1.f); }
                    }
                }
            }
            // full middle 512-chunks: no predicates
            int j0 = base + 512;
            for (; j0 + 512 <= N; j0 += 512) {
                const int   j1 = j0 + tid, j2 = j0 + 256 + tid;
                const float ax = x[j1], ay = y[j1], az = z[j1];
                const float bx = x[j2], by = y[j2], bz = z[j2];
#pragma unroll
                for (int r = 0; r < 8; ++r) {
                    const float dx1 = ax - xr[ro + r], dy1 = ay - yr[ro + r], dz1 = az - zr[ro + r];
                    const float d1  = fsqrt(dx1 * dx1 + dy1 * dy1 + dz1 * dz1);
                    const float dx2 = bx - xr[ro + r], dy2 = by - yr[ro + r], dz2 = bz - zr[ro + r];
                    const float d2  = fsqrt(dx2 * dx2 + dy2 * dy2 + dz2 * dz2);
                    sd[ro + r] += d1 + d2;
                    sm[ro + r] += fminf(d1, 1.f) + fminf(d2, 1.f);
                }
            }
            // tail: predicated 256-chunks
            for (; j0 < N; j0 += 256) {
                const int   j = j0 + tid;
                const int   c = j < N ? j : N - 1;
                const float ax = x[c], ay = y[c], az = z[c];
                if (j < N) {
#pragma unroll
                    for (int r = 0; r < 8; ++r) {
                        const float dx = ax - xr[ro + r], dy = ay - yr[ro + r], dz = az - zr[ro + r];
                        const float d  = fsqrt(dx * dx + dy * dy + dz * dz);
                        sd[ro + r] += d; sm[ro + r] += fminf(d, 1.f);
                    }
                }
            }
        }

        // reduce 16 rows across the block
        __shared__ float lsd[4][16];
        __shared__ float lsm[4][16];
#pragma unroll
        for (int r = 0; r < 16; ++r) {
            float a = sd[r], c = sm[r];
#pragma unroll
            for (int off = 32; off; off >>= 1) {
                a += __shfl_down(a, off);
                c += __shfl_down(c, off);
            }
            if (lane == 0) { lsd[wave][r] = a; lsm[wave][r] = c; }
        }
        __syncthreads();
        if (tid < 16) {
            const float a = lsd[0][tid] + lsd[1][tid] + lsd[2][tid] + lsd[3][tid];
            const float c = lsm[0][tid] + lsm[1][tid] + lsm[2][tid] + lsm[3][tid];
            const int   i = (tid < 8) ? (topBase + tid) : (botBase + tid - 8);
            row_sd[i] = a;
            row_sm[i] = c;
        }
    } else {
        // masked-prefix-run correction: 32 rows/block, 8 rows per wave
        const int cb = blockIdx.x - 512;
#pragma unroll
        for (int rr = 0; rr < 8; ++rr) {
            const int   i  = 32 * cb + 8 * wave + rr;
            const float xi = x[i], yi = y[i], zi = z[i];
            float corr = 0.f;
            for (int jb = i; jb < N; jb += 64) {
                const int j = jb + lane;
                float d = 2.f;
                if (j < N) {
                    const float dx = x[j] - xi, dy = y[j] - yi, dz = z[j] - zi;
                    d = fsqrt(dx * dx + dy * dy + dz * dz);
                }
                const unsigned long long far = __ballot(d > 1.0f);
                const int stop = far ? __builtin_ctzll(far) : 64;
                if (lane < stop) corr += 1.f - d;
                if (far) break;
            }
#pragma unroll
            for (int off = 32; off; off >>= 1) corr += __shfl_down(corr, off);
            if (lane == 0) row_corr[i] = corr;
        }
    }
}

// Single block, deterministic:
//   A = sum row_sd, M = sum row_sm, C = sum row_corr
//   sum_dist = 2A;  sum_relu = 2*(TRI - M) - N;  intersect = sum_relu - C
__global__ __launch_bounds__(256)
void finalize_kernel(const float* __restrict__ y, const float* __restrict__ z,
                     const float* __restrict__ row_sd, const float* __restrict__ row_sm,
                     const float* __restrict__ row_corr, float* __restrict__ out) {
    const int tid = threadIdx.x;
    float A = 0.f, M = 0.f, C = 0.f, sfix = 0.f, snoise = 0.f;
    for (int i = tid; i < N; i += 256) {
        A += row_sd[i];
        M += row_sm[i];
        C += row_corr[i];
        const float yv = y[i], zv = z[i];
        sfix += fmaxf(yv - 1.f, 0.f) + fmaxf(-1.f - yv, 0.f)
              + fmaxf(zv - 1.f, 0.f) + fmaxf(-1.f - zv, 0.f);
        if (i < N - 2) {
            const float d2y = y[i + 2] - 2.f * y[i + 1] + y[i];
            const float d2z = z[i + 2] - 2.f * z[i + 1] + z[i];
            snoise += d2y * d2y + d2z * d2z;
        }
    }
    __shared__ float s[5][256];
    s[0][tid] = A; s[1][tid] = M; s[2][tid] = C; s[3][tid] = sfix; s[4][tid] = snoise;
    __syncthreads();
    for (int st = 128; st; st >>= 1) {
        if (tid < st) {
#pragma unroll
            for (int k = 0; k < 5; ++k) s[k][tid] += s[k][tid + st];
        }
        __syncthreads();
    }
    if (tid == 0)
        out[0] = s[3][0] + (2.f * s[0][0]) / 10000.f
               + (2.f * (TRI - s[1][0]) - (float)N - s[2][0]) + 10.f * s[4][0];
}

extern "C" void kernel_launch(void* const* d_in, const int* in_sizes, int n_in,
                              void* d_out, int out_size, void* d_ws, size_t ws_size,
                              hipStream_t stream) {
    const float* x = (const float*)d_in[0];
    const float* y = (const float*)d_in[1];
    const float* z = (const float*)d_in[2];
    float* out      = (float*)d_out;
    float* row_sd   = (float*)d_ws;
    float* row_sm   = row_sd + N;
    float* row_corr = row_sm + N;

    main_kernel<<<768, 256, 0, stream>>>(x, y, z, row_sd, row_sm, row_corr);
    finalize_kernel<<<1, 256, 0, stream>>>(y, z, row_sd, row_sm, row_corr, out);
}

// Round 5
// 35.776 us; speedup vs baseline: 1.2985x; 1.2985x over previous
//
#include <hip/hip_runtime.h>

constexpr int N = 8192;
// MIN_DIST = RADIUS*2*scale = 1.0f;  TRI = N(N+1)/2, exact in f32
constexpr float TRI = 33558528.0f;

__device__ __forceinline__ float fsqrt(float v) { return __builtin_amdgcn_sqrtf(v); }

// Fused kernel, 2048 blocks (8 blocks/CU -> 8 waves/SIMD):
//  blocks [0,1024):    pair tiles — 8 rows: {4b..4b+3} (top) + {N-4b-4..N-4b-1} (bot),
//                      upper-triangle scan j >= i, 2 j's per lane, preloaded.
//                        row_sd[i] = sum_{j>=i} d(i,j)
//                        row_sm[i] = sum_{j>=i} min(d,1)
//  blocks [1024,2048): masked-prefix-run correction, 8 rows/block, 2 rows/wave:
//                        row_corr[i] = sum over run [i,k) of (1-d), k = first d>1.
__global__ __launch_bounds__(256, 4)
void main_kernel(const float* __restrict__ x, const float* __restrict__ y,
                 const float* __restrict__ z,
                 float* __restrict__ row_sd, float* __restrict__ row_sm,
                 float* __restrict__ row_corr) {
    const int tid  = threadIdx.x;
    const int lane = tid & 63;
    const int wave = tid >> 6;

    if (blockIdx.x < 1024) {
        const int b       = blockIdx.x;
        const int topBase = 4 * b;            // 0..4092
        const int botBase = N - 4 * (b + 1);  // 8188..4096

        // Row coordinates: block-uniform -> SGPRs.
        float xr[8], yr[8], zr[8];
#pragma unroll
        for (int r = 0; r < 4; ++r) {
            xr[r]     = x[topBase + r]; yr[r]     = y[topBase + r]; zr[r]     = z[topBase + r];
            xr[4 + r] = x[botBase + r]; yr[4 + r] = y[botBase + r]; zr[4 + r] = z[botBase + r];
        }
        float sd[8], sm[8];
#pragma unroll
        for (int r = 0; r < 8; ++r) { sd[r] = 0.f; sm[r] = 0.f; }

#pragma unroll
        for (int g = 0; g < 2; ++g) {
            const int base = g ? botBase : topBase;
            const int ro   = g * 4;

            // head chunk [base, base+512): predicated vs diagonal and N
            {
                const int   j1 = base + tid;
                const int   j2 = base + 256 + tid;
                const int   c1 = j1 < N ? j1 : N - 1;
                const int   c2 = j2 < N ? j2 : N - 1;
                const float ax = x[c1], ay = y[c1], az = z[c1];
                const float bx = x[c2], by = y[c2], bz = z[c2];
#pragma unroll
                for (int r = 0; r < 4; ++r) {
                    const float dx1 = ax - xr[ro + r], dy1 = ay - yr[ro + r], dz1 = az - zr[ro + r];
                    const float d1  = fsqrt(dx1 * dx1 + dy1 * dy1 + dz1 * dz1);
                    const float dx2 = bx - xr[ro + r], dy2 = by - yr[ro + r], dz2 = bz - zr[ro + r];
                    const float d2  = fsqrt(dx2 * dx2 + dy2 * dy2 + dz2 * dz2);
                    if (tid >= r && j1 < N) { sd[ro + r] += d1; sm[ro + r] += fminf(d1, 1.f); }
                    if (j2 < N)             { sd[ro + r] += d2; sm[ro + r] += fminf(d2, 1.f); }
                }
            }
            // full middle 512-chunks: predicate-free, software-pipelined preload
            int j0 = base + 512;
            if (j0 + 512 <= N) {
                float ax = x[j0 + tid],       ay = y[j0 + tid],       az = z[j0 + tid];
                float bx = x[j0 + 256 + tid], by = y[j0 + 256 + tid], bz = z[j0 + 256 + tid];
                while (true) {
                    const float cax = ax, cay = ay, caz = az;
                    const float cbx = bx, cby = by, cbz = bz;
                    const bool  more = (j0 + 1024 <= N);
                    if (more) {
                        const int n1 = j0 + 512 + tid, n2 = j0 + 768 + tid;
                        ax = x[n1]; ay = y[n1]; az = z[n1];
                        bx = x[n2]; by = y[n2]; bz = z[n2];
                    }
#pragma unroll
                    for (int r = 0; r < 4; ++r) {
                        const float dx1 = cax - xr[ro + r], dy1 = cay - yr[ro + r], dz1 = caz - zr[ro + r];
                        const float d1  = fsqrt(dx1 * dx1 + dy1 * dy1 + dz1 * dz1);
                        const float dx2 = cbx - xr[ro + r], dy2 = cby - yr[ro + r], dz2 = cbz - zr[ro + r];
                        const float d2  = fsqrt(dx2 * dx2 + dy2 * dy2 + dz2 * dz2);
                        sd[ro + r] += d1 + d2;
                        sm[ro + r] += fminf(d1, 1.f) + fminf(d2, 1.f);
                    }
                    j0 += 512;
                    if (!more) break;
                }
            }
            // tail: predicated 256-chunks
            for (; j0 < N; j0 += 256) {
                const int   j = j0 + tid;
                const int   c = j < N ? j : N - 1;
                const float ax = x[c], ay = y[c], az = z[c];
                if (j < N) {
#pragma unroll
                    for (int r = 0; r < 4; ++r) {
                        const float dx = ax - xr[ro + r], dy = ay - yr[ro + r], dz = az - zr[ro + r];
                        const float d  = fsqrt(dx * dx + dy * dy + dz * dz);
                        sd[ro + r] += d; sm[ro + r] += fminf(d, 1.f);
                    }
                }
            }
        }

        // reduce 8 rows across the block
        __shared__ float lsd[4][8];
        __shared__ float lsm[4][8];
#pragma unroll
        for (int r = 0; r < 8; ++r) {
            float a = sd[r], c = sm[r];
#pragma unroll
            for (int off = 32; off; off >>= 1) {
                a += __shfl_down(a, off);
                c += __shfl_down(c, off);
            }
            if (lane == 0) { lsd[wave][r] = a; lsm[wave][r] = c; }
        }
        __syncthreads();
        if (tid < 8) {
            const float a = lsd[0][tid] + lsd[1][tid] + lsd[2][tid] + lsd[3][tid];
            const float c = lsm[0][tid] + lsm[1][tid] + lsm[2][tid] + lsm[3][tid];
            const int   i = (tid < 4) ? (topBase + tid) : (botBase + tid - 4);
            row_sd[i] = a;
            row_sm[i] = c;
        }
    } else {
        // masked-prefix-run correction: 8 rows/block, 2 rows/wave, preloaded scan
        const int cb = blockIdx.x - 1024;
#pragma unroll
        for (int rr = 0; rr < 2; ++rr) {
            const int   i  = 8 * cb + 2 * wave + rr;
            const float xi = x[i], yi = y[i], zi = z[i];
            float corr = 0.f;
            int   jb   = i;
            int   c0   = (i + lane < N) ? (i + lane) : (N - 1);
            float px = x[c0], py = y[c0], pz = z[c0];
            while (jb < N) {
                const int   j  = jb + lane;
                const float cx = px, cy = py, cz = pz;
                const int   jn = jb + 64 + lane;
                const int   cn = jn < N ? jn : N - 1;
                px = x[cn]; py = y[cn]; pz = z[cn];

                const float dx = cx - xi, dy = cy - yi, dz = cz - zi;
                float d = fsqrt(dx * dx + dy * dy + dz * dz);
                if (j >= N) d = 2.f;
                const unsigned long long far = __ballot(d > 1.0f);
                const int stop = far ? __builtin_ctzll(far) : 64;
                if (lane < stop) corr += 1.f - d;
                if (far) break;
                jb += 64;
            }
#pragma unroll
            for (int off = 32; off; off >>= 1) corr += __shfl_down(corr, off);
            if (lane == 0) row_corr[i] = corr;
        }
    }
}

// Single block, deterministic:
//   A = sum row_sd, M = sum row_sm, C = sum row_corr
//   sum_dist = 2A;  sum_relu = 2*(TRI - M) - N;  intersect = sum_relu - C
__global__ __launch_bounds__(256)
void finalize_kernel(const float* __restrict__ y, const float* __restrict__ z,
                     const float* __restrict__ row_sd, const float* __restrict__ row_sm,
                     const float* __restrict__ row_corr, float* __restrict__ out) {
    const int tid = threadIdx.x;
    float A = 0.f, M = 0.f, C = 0.f, sfix = 0.f, snoise = 0.f;
    for (int i = tid; i < N; i += 256) {
        A += row_sd[i];
        M += row_sm[i];
        C += row_corr[i];
        const float yv = y[i], zv = z[i];
        sfix += fmaxf(yv - 1.f, 0.f) + fmaxf(-1.f - yv, 0.f)
              + fmaxf(zv - 1.f, 0.f) + fmaxf(-1.f - zv, 0.f);
        if (i < N - 2) {
            const float d2y = y[i + 2] - 2.f * y[i + 1] + y[i];
            const float d2z = z[i + 2] - 2.f * z[i + 1] + z[i];
            snoise += d2y * d2y + d2z * d2z;
        }
    }
    __shared__ float s[5][256];
    s[0][tid] = A; s[1][tid] = M; s[2][tid] = C; s[3][tid] = sfix; s[4][tid] = snoise;
    __syncthreads();
    for (int st = 128; st; st >>= 1) {
        if (tid < st) {
#pragma unroll
            for (int k = 0; k < 5; ++k) s[k][tid] += s[k][tid + st];
        }
        __syncthreads();
    }
    if (tid == 0)
        out[0] = s[3][0] + (2.f * s[0][0]) / 10000.f
               + (2.f * (TRI - s[1][0]) - (float)N - s[2][0]) + 10.f * s[4][0];
}

extern "C" void kernel_launch(void* const* d_in, const int* in_sizes, int n_in,
                              void* d_out, int out_size, void* d_ws, size_t ws_size,
                              hipStream_t stream) {
    const float* x = (const float*)d_in[0];
    const float* y = (const float*)d_in[1];
    const float* z = (const float*)d_in[2];
    float* out      = (float*)d_out;
    float* row_sd   = (float*)d_ws;
    float* row_sm   = row_sd + N;
    float* row_corr = row_sm + N;

    main_kernel<<<2048, 256, 0, stream>>>(x, y, z, row_sd, row_sm, row_corr);
    finalize_kernel<<<1, 256, 0, stream>>>(y, z, row_sd, row_sm, row_corr, out);
}